// Round 10
// baseline (370.999 us; speedup 1.0000x reference)
//
#include <hip/hip_runtime.h>
#include <hip/hip_fp16.h>
#include <cstdint>

typedef _Float16 f16x8 __attribute__((ext_vector_type(8)));
typedef _Float16 f16x4 __attribute__((ext_vector_type(4)));
typedef float    f32x4 __attribute__((ext_vector_type(4)));

#define MFMA16(a, b, c) __builtin_amdgcn_mfma_f32_16x16x32_f16((a), (b), (c), 0, 0, 0)

// async global->LDS, 16B per lane; LDS dest = wave-uniform base + lane*16
__device__ __forceinline__ void async16(_Float16* lds, const _Float16* g) {
    __builtin_amdgcn_global_load_lds(
        (const __attribute__((address_space(1))) void*)g,
        (__attribute__((address_space(3))) void*)lds, 16, 0, 0);
}

// ---------------------------------------------------------------------------
// fp32 -> fp16 convert, 8 elems/thread, exact grid
// ---------------------------------------------------------------------------
__global__ __launch_bounds__(256) void k_cvt(
    const float* __restrict__ src, _Float16* __restrict__ dst)
{
    const int i = blockIdx.x * 256 + threadIdx.x;
    const float4 a = ((const float4*)src)[2 * i];
    const float4 b = ((const float4*)src)[2 * i + 1];
    f16x8 o = { (_Float16)a.x, (_Float16)a.y, (_Float16)a.z, (_Float16)a.w,
                (_Float16)b.x, (_Float16)b.y, (_Float16)b.z, (_Float16)b.w };
    ((f16x8*)dst)[i] = o;
}

// ---------------------------------------------------------------------------
// Materialize bias matrix bm[h][i][j] fp16 (16 x 256 x 256 = 2 MB).
// grid = 16*256 blocks (h,i); thread j.
// ---------------------------------------------------------------------------
__global__ __launch_bounds__(256) void k_bias(
    const float* __restrict__ rpb, _Float16* __restrict__ bm)
{
    const int i = blockIdx.x & 255, j = threadIdx.x, h = blockIdx.x >> 8;
    const int ih = i >> 5, iw = i & 31, jh = j >> 5, jw = j & 31;
    const int idx = (ih - jh + 7) * 63 + (iw - jw + 31);
    bm[(size_t)blockIdx.x * 256 + j] = (_Float16)rpb[idx * 16 + h];
}

// ---------------------------------------------------------------------------
// fp16 GEMM (qkv): C[m][n] = sum_k A[m][k]*B[n][k] + bias[n], fp16 out.
// 128x128 tile, BK=64, 4 waves. global_load_lds w16, linear LDS dest +
// inverse-swizzled source (rule 21); XCD-swizzled 1D grid (T1).
// ---------------------------------------------------------------------------
__global__ __launch_bounds__(256) void k_gemm_f16(
    const _Float16* __restrict__ A, int lda,
    const _Float16* __restrict__ B, int ldb,
    const float* __restrict__ bias,
    _Float16* __restrict__ C, int ldc,
    int K, int nTilesN, int cpx)
{
    __shared__ _Float16 lA[128 * 64];
    __shared__ _Float16 lB[128 * 64];
    const int t    = threadIdx.x;
    const int lane = t & 63, wv = t >> 6;
    const int fr = lane & 15, fg = lane >> 4;
    const int wrow = (wv >> 1) * 64, wcol = (wv & 1) * 64;

    const int gid  = (blockIdx.x & 7) * cpx + (blockIdx.x >> 3);
    const int row0 = (gid / nTilesN) * 128;
    const int col0 = (gid % nTilesN) * 128;

    const int rowLane = lane >> 3;
    const int colOff  = ((lane & 7) ^ rowLane) * 8;
    const int wvr = wv * 32;

    const _Float16* Ag = A + (size_t)(row0 + wvr + rowLane) * lda + colOff;
    const _Float16* Bg = B + (size_t)(col0 + wvr + rowLane) * ldb + colOff;
    _Float16* lAw = &lA[wvr * 64];
    _Float16* lBw = &lB[wvr * 64];

    f32x4 acc[4][4] = {};

    for (int k0 = 0; k0 < K; k0 += 64) {
#pragma unroll
        for (int i = 0; i < 4; ++i) {
            async16(lAw + i * 8 * 64, Ag + k0 + (size_t)i * 8 * lda);
            async16(lBw + i * 8 * 64, Bg + k0 + (size_t)i * 8 * ldb);
        }
        __syncthreads();
#pragma unroll
        for (int kk = 0; kk < 2; ++kk) {
            f16x8 af[4], bf[4];
#pragma unroll
            for (int mi = 0; mi < 4; ++mi) {
                const int ra = wrow + mi * 16 + fr;
                const int rb = wcol + mi * 16 + fr;
                const int ch = ((kk * 4 + fg) ^ (fr & 7)) * 8;
                af[mi] = *(const f16x8*)&lA[ra * 64 + ch];
                bf[mi] = *(const f16x8*)&lB[rb * 64 + ch];
            }
#pragma unroll
            for (int mi = 0; mi < 4; ++mi)
#pragma unroll
                for (int ni = 0; ni < 4; ++ni)
                    acc[mi][ni] = MFMA16(af[mi], bf[ni], acc[mi][ni]);
        }
        __syncthreads();
    }
#pragma unroll
    for (int ni = 0; ni < 4; ++ni) {
        const int col = col0 + wcol + ni * 16 + fr;
        const float bb = bias[col];
#pragma unroll
        for (int mi = 0; mi < 4; ++mi)
#pragma unroll
            for (int r = 0; r < 4; ++r) {
                const int row = row0 + wrow + mi * 16 + fg * 4 + r;
                C[(size_t)row * ldc + col] = (_Float16)(acc[mi][ni][r] + bb);
            }
    }
}

// ---------------------------------------------------------------------------
// Proj GEMM, 128x128 tile: A fp16 via global_load_lds (lda=1536, q-slice),
// B fp32 reg-staged + cvt into swizzled LDS slot (1 MB, L2-resident),
// C fp32 + bias.
// ---------------------------------------------------------------------------
__global__ __launch_bounds__(256) void k_gemm_pf32(
    const _Float16* __restrict__ A, int lda,
    const float* __restrict__ B, int ldb,
    const float* __restrict__ bias,
    float* __restrict__ C, int ldc,
    int K, int nTilesN, int cpx)
{
    __shared__ _Float16 lA[128 * 64];
    __shared__ _Float16 lB[128 * 64];
    const int t    = threadIdx.x;
    const int lane = t & 63, wv = t >> 6;
    const int fr = lane & 15, fg = lane >> 4;
    const int wrow = (wv >> 1) * 64, wcol = (wv & 1) * 64;

    const int gid  = (blockIdx.x & 7) * cpx + (blockIdx.x >> 3);
    const int row0 = (gid / nTilesN) * 128;
    const int col0 = (gid % nTilesN) * 128;

    const int rowLane = lane >> 3;
    const int colOff  = ((lane & 7) ^ rowLane) * 8;
    const int wvr = wv * 32;

    const _Float16* Ag = A + (size_t)(row0 + wvr + rowLane) * lda + colOff;
    _Float16* lAw = &lA[wvr * 64];

    // B staging: thread t owns row sb = t>>1, cols cb..cb+31 (fp32 -> fp16)
    const int sb = t >> 1, cb = (t & 1) * 32;
    const float* Bg = B + (size_t)(col0 + sb) * ldb + cb;

    f32x4 acc[4][4] = {};

    for (int k0 = 0; k0 < K; k0 += 64) {
#pragma unroll
        for (int i = 0; i < 4; ++i)
            async16(lAw + i * 8 * 64, Ag + k0 + (size_t)i * 8 * lda);
#pragma unroll
        for (int c = 0; c < 4; ++c) {
            float4 u = *(const float4*)(Bg + k0 + c * 8);
            float4 v = *(const float4*)(Bg + k0 + c * 8 + 4);
            f16x8 hv = { (_Float16)u.x, (_Float16)u.y, (_Float16)u.z, (_Float16)u.w,
                         (_Float16)v.x, (_Float16)v.y, (_Float16)v.z, (_Float16)v.w };
            const int ch = (cb >> 3) + c;               // logical chunk 0..7
            *(f16x8*)&lB[sb * 64 + ((ch ^ (sb & 7)) * 8)] = hv;
        }
        __syncthreads();
#pragma unroll
        for (int kk = 0; kk < 2; ++kk) {
            f16x8 af[4], bf[4];
#pragma unroll
            for (int mi = 0; mi < 4; ++mi) {
                const int ra = wrow + mi * 16 + fr;
                const int rb = wcol + mi * 16 + fr;
                const int ch = ((kk * 4 + fg) ^ (fr & 7)) * 8;
                af[mi] = *(const f16x8*)&lA[ra * 64 + ch];
                bf[mi] = *(const f16x8*)&lB[rb * 64 + ch];
            }
#pragma unroll
            for (int mi = 0; mi < 4; ++mi)
#pragma unroll
                for (int ni = 0; ni < 4; ++ni)
                    acc[mi][ni] = MFMA16(af[mi], bf[ni], acc[mi][ni]);
        }
        __syncthreads();
    }
#pragma unroll
    for (int ni = 0; ni < 4; ++ni) {
        const int col = col0 + wcol + ni * 16 + fr;
        const float bb = bias[col];
#pragma unroll
        for (int mi = 0; mi < 4; ++mi)
#pragma unroll
            for (int r = 0; r < 4; ++r) {
                const int row = row0 + wrow + mi * 16 + fg * 4 + r;
                C[(size_t)row * ldc + col] = acc[mi][ni][r] + bb;
            }
    }
}

// ---------------------------------------------------------------------------
// Attention v2: one block (4 waves) per (b,h); in-place q-slice output.
// pass1 = pure QK^T -> lS. pass2 = vector bias add (precomputed bm) + in-lane
// row max (lane holds 64 of row fr's 256 cols) + exp + sum. No lbias LDS ->
// 50.7 KB -> 3 blocks/CU.
// ---------------------------------------------------------------------------
#define ATT_SCALE 0.17677669529663687f  // 1/sqrt(32)

__global__ __launch_bounds__(256) void k_attn(
    _Float16* __restrict__ qkv, const _Float16* __restrict__ bm)
{
    __shared__ _Float16 lS[4][16 * 264];
    __shared__ _Float16 lVt[32 * 264];

    const int bh = blockIdx.x;
    const int b = bh >> 4, h = bh & 15;
    const int t = threadIdx.x, wv = t >> 6, lane = t & 63;
    const int fr = lane & 15, fg = lane >> 4;

    _Float16* qkv_b0 = qkv + (size_t)b * 256 * 1536;
    const _Float16* bias_h = bm + (size_t)h * 256 * 256;

    // V transposed into LDS: thread t owns V row t (32 halves)
    {
        const _Float16* vrow = qkv_b0 + (size_t)t * 1536 + 1024 + h * 32;
        f16x8 v0 = *(const f16x8*)(vrow);
        f16x8 v1 = *(const f16x8*)(vrow + 8);
        f16x8 v2 = *(const f16x8*)(vrow + 16);
        f16x8 v3 = *(const f16x8*)(vrow + 24);
#pragma unroll
        for (int d = 0; d < 8; ++d) {
            lVt[(d     ) * 264 + t] = v0[d];
            lVt[(d +  8) * 264 + t] = v1[d];
            lVt[(d + 16) * 264 + t] = v2[d];
            lVt[(d + 24) * 264 + t] = v3[d];
        }
    }
    __syncthreads();

    _Float16* myS = &lS[wv][0];

    for (int rb = 0; rb < 4; ++rb) {
        const int r0 = wv * 64 + rb * 16;

        f16x8 aq = *(const f16x8*)(qkv_b0 + (size_t)(r0 + fr) * 1536 + h * 32 + fg * 8);

        // ---- pass 1: pure QK^T -> lS (fp16, scaled) ----
#pragma unroll 4
        for (int jt = 0; jt < 16; ++jt) {
            f16x8 bk = *(const f16x8*)(qkv_b0 + (size_t)(jt * 16 + fr) * 1536 + 512 + h * 32 + fg * 8);
            f32x4 s = { 0.f, 0.f, 0.f, 0.f };
            s = MFMA16(aq, bk, s);
#pragma unroll
            for (int r = 0; r < 4; ++r)
                myS[(fg * 4 + r) * 264 + jt * 16 + fr] = (_Float16)(s[r] * ATT_SCALE);
        }

        // bias row chunks (global, L2-resident; independent of LDS wait)
        f16x8 tb[8];
        {
            const _Float16* brow = bias_h + (size_t)(r0 + fr) * 256 + fg * 8;
#pragma unroll
            for (int kc = 0; kc < 8; ++kc)
                tb[kc] = *(const f16x8*)(brow + kc * 32);
        }
        // wave-internal: pass-1 S writes must land before pass-2 reads
        asm volatile("s_waitcnt lgkmcnt(0)" ::: "memory");

        // ---- pass 2: S+bias, in-lane 64-val max, exp, sum ----
        float vmax = -1e30f;
#pragma unroll
        for (int kc = 0; kc < 8; ++kc) {
            f16x8 sv = *(const f16x8*)(&myS[fr * 264 + kc * 32 + fg * 8]);
            tb[kc] = tb[kc] + sv;
#pragma unroll
            for (int j = 0; j < 8; ++j)
                vmax = fmaxf(vmax, (float)tb[kc][j]);
        }
        vmax = fmaxf(vmax, __shfl_xor(vmax, 16));
        vmax = fmaxf(vmax, __shfl_xor(vmax, 32));

        float rsum = 0.f;
#pragma unroll
        for (int kc = 0; kc < 8; ++kc) {
#pragma unroll
            for (int j = 0; j < 8; ++j) {
                float p = __expf((float)tb[kc][j] - vmax);
                rsum += p;
                tb[kc][j] = (_Float16)p;      // tb becomes the P A-fragment
            }
        }
        rsum += __shfl_xor(rsum, 16);
        rsum += __shfl_xor(rsum, 32);

        // ---- PV ----
        f32x4 o[2] = {};
#pragma unroll
        for (int kc = 0; kc < 8; ++kc) {
            f16x8 bv0 = *(const f16x8*)(&lVt[(fr     ) * 264 + kc * 32 + fg * 8]);
            f16x8 bv1 = *(const f16x8*)(&lVt[(fr + 16) * 264 + kc * 32 + fg * 8]);
            o[0] = MFMA16(tb[kc], bv0, o[0]);
            o[1] = MFMA16(tb[kc], bv1, o[1]);
        }
        float os[4];
#pragma unroll
        for (int r = 0; r < 4; ++r) os[r] = __shfl(rsum, fg * 4 + r);

#pragma unroll
        for (int ni = 0; ni < 2; ++ni)
#pragma unroll
            for (int r = 0; r < 4; ++r) {
                const int i = r0 + fg * 4 + r;
                const int d = ni * 16 + fr;
                qkv_b0[(size_t)i * 1536 + h * 32 + d] = (_Float16)(o[ni][r] / os[r]);
            }
    }
}

// ---------------------------------------------------------------------------
extern "C" void kernel_launch(void* const* d_in, const int* in_sizes, int n_in,
                              void* d_out, int out_size, void* d_ws, size_t ws_size,
                              hipStream_t stream)
{
    (void)in_sizes; (void)n_in;
    const float* x      = (const float*)d_in[0];
    const float* qkv_w  = (const float*)d_in[2];
    const float* qkv_b  = (const float*)d_in[3];
    const float* proj_w = (const float*)d_in[4];
    const float* proj_b = (const float*)d_in[5];
    const float* rpb    = (const float*)d_in[6];
    float* out = (float*)d_out;

    const int M  = 128 * 256;  // 32768
    const int Cd = 512, N3 = 1536;

    // ws: qkv fp16 (96 MB). d_out (64 MB) doubles as scratch: xh (32 MB),
    // qwh (1.5 MB), bm (2 MB) — all dead before proj overwrites d_out.
    const size_t need = (size_t)M * N3 * sizeof(_Float16);
    if (ws_size < need) {
        (void)hipMemsetAsync(d_out, 0, (size_t)out_size * sizeof(float), stream);
        return;
    }

    _Float16* qkvh = (_Float16*)d_ws;
    _Float16* xh   = (_Float16*)d_out;                    // 32 MB
    _Float16* qwh  = xh + (size_t)M * Cd;                 // +1.5 MB
    _Float16* bmat = qwh + (size_t)N3 * Cd;               // +2 MB (ends 35.5 MB)

    k_cvt<<<dim3((M * Cd) / 2048), 256, 0, stream>>>(x, xh);
    k_cvt<<<dim3((N3 * Cd) / 2048), 256, 0, stream>>>(qkv_w, qwh);
    k_bias<<<dim3(16 * 256), 256, 0, stream>>>(rpb, bmat);

    k_gemm_f16<<<dim3(3072), 256, 0, stream>>>(xh, Cd, qwh, Cd, qkv_b,
                                               qkvh, N3, Cd, 12, 384);
    k_attn<<<dim3(128 * 16), 256, 0, stream>>>(qkvh, bmat);
    k_gemm_pf32<<<dim3(1024), 256, 0, stream>>>(qkvh, N3, proj_w, Cd, proj_b,
                                                out, Cd, Cd, 4, 128);
}

// Round 11
// 347.444 us; speedup vs baseline: 1.0678x; 1.0678x over previous
//
#include <hip/hip_runtime.h>
#include <hip/hip_fp16.h>
#include <cstdint>

typedef _Float16 f16x8 __attribute__((ext_vector_type(8)));
typedef _Float16 f16x4 __attribute__((ext_vector_type(4)));
typedef float    f32x4 __attribute__((ext_vector_type(4)));

#define MFMA16(a, b, c) __builtin_amdgcn_mfma_f32_16x16x32_f16((a), (b), (c), 0, 0, 0)

// async global->LDS, 16B per lane; LDS dest = wave-uniform base + lane*16
__device__ __forceinline__ void async16(_Float16* lds, const _Float16* g) {
    __builtin_amdgcn_global_load_lds(
        (const __attribute__((address_space(1))) void*)g,
        (__attribute__((address_space(3))) void*)lds, 16, 0, 0);
}

// ---------------------------------------------------------------------------
// fp32 -> fp16 convert, 8 elems/thread, exact grid
// ---------------------------------------------------------------------------
__global__ __launch_bounds__(256) void k_cvt(
    const float* __restrict__ src, _Float16* __restrict__ dst)
{
    const int i = blockIdx.x * 256 + threadIdx.x;
    const float4 a = ((const float4*)src)[2 * i];
    const float4 b = ((const float4*)src)[2 * i + 1];
    f16x8 o = { (_Float16)a.x, (_Float16)a.y, (_Float16)a.z, (_Float16)a.w,
                (_Float16)b.x, (_Float16)b.y, (_Float16)b.z, (_Float16)b.w };
    ((f16x8*)dst)[i] = o;
}

// ---------------------------------------------------------------------------
// Materialize bias matrix bm[h][i][j] fp16 (16 x 256 x 256 = 2 MB).
// ---------------------------------------------------------------------------
__global__ __launch_bounds__(256) void k_bias(
    const float* __restrict__ rpb, _Float16* __restrict__ bm)
{
    const int i = blockIdx.x & 255, j = threadIdx.x, h = blockIdx.x >> 8;
    const int ih = i >> 5, iw = i & 31, jh = j >> 5, jw = j & 31;
    const int idx = (ih - jh + 7) * 63 + (iw - jw + 31);
    bm[(size_t)blockIdx.x * 256 + j] = (_Float16)rpb[idx * 16 + h];
}

// ---------------------------------------------------------------------------
// qkv GEMM: out[m][n] = sum_k x[m][k]*W[n][k] + bias[n], written HEAD-MAJOR:
// n -> (which,h,d); store to {Q,K,V}[h][b][nrow][32].  128x128 tile, BK=64,
// global_load_lds w16, linear LDS dest + inverse-swizzled source (rule 21),
// XCD-swizzled 1D grid (T1).
// ---------------------------------------------------------------------------
__global__ __launch_bounds__(256) void k_gemm_qkv(
    const _Float16* __restrict__ A, int lda,
    const _Float16* __restrict__ Bm, int ldb,
    const float* __restrict__ bias,
    _Float16* __restrict__ Qh, _Float16* __restrict__ Kh,
    _Float16* __restrict__ Vh,
    int K, int nTilesN, int cpx)
{
    __shared__ _Float16 lA[128 * 64];
    __shared__ _Float16 lB[128 * 64];
    const int t    = threadIdx.x;
    const int lane = t & 63, wv = t >> 6;
    const int fr = lane & 15, fg = lane >> 4;
    const int wrow = (wv >> 1) * 64, wcol = (wv & 1) * 64;

    const int gid  = (blockIdx.x & 7) * cpx + (blockIdx.x >> 3);
    const int row0 = (gid / nTilesN) * 128;
    const int col0 = (gid % nTilesN) * 128;

    const int rowLane = lane >> 3;
    const int colOff  = ((lane & 7) ^ rowLane) * 8;
    const int wvr = wv * 32;

    const _Float16* Ag = A + (size_t)(row0 + wvr + rowLane) * lda + colOff;
    const _Float16* Bg = Bm + (size_t)(col0 + wvr + rowLane) * ldb + colOff;
    _Float16* lAw = &lA[wvr * 64];
    _Float16* lBw = &lB[wvr * 64];

    f32x4 acc[4][4] = {};

    for (int k0 = 0; k0 < K; k0 += 64) {
#pragma unroll
        for (int i = 0; i < 4; ++i) {
            async16(lAw + i * 8 * 64, Ag + k0 + (size_t)i * 8 * lda);
            async16(lBw + i * 8 * 64, Bg + k0 + (size_t)i * 8 * ldb);
        }
        __syncthreads();
#pragma unroll
        for (int kk = 0; kk < 2; ++kk) {
            f16x8 af[4], bf[4];
#pragma unroll
            for (int mi = 0; mi < 4; ++mi) {
                const int ra = wrow + mi * 16 + fr;
                const int rb = wcol + mi * 16 + fr;
                const int ch = ((kk * 4 + fg) ^ (fr & 7)) * 8;
                af[mi] = *(const f16x8*)&lA[ra * 64 + ch];
                bf[mi] = *(const f16x8*)&lB[rb * 64 + ch];
            }
#pragma unroll
            for (int mi = 0; mi < 4; ++mi)
#pragma unroll
                for (int ni = 0; ni < 4; ++ni)
                    acc[mi][ni] = MFMA16(af[mi], bf[ni], acc[mi][ni]);
        }
        __syncthreads();
    }

    // head-major epilogue. 128-col tile stays within one of {q,k,v} (512%128
    // ==0); each 16-col group stays within one head (d0 in {0,16}).
    const int b  = row0 >> 8;     // batch const per block (128 | 256)
    const int nb = row0 & 255;    // row base within batch
#pragma unroll
    for (int ni = 0; ni < 4; ++ni) {
        const int colb  = col0 + wcol + ni * 16;
        const int which = colb >> 9;
        const int h     = (colb >> 5) & 15;
        const int d0    = colb & 31;
        _Float16* T = which == 0 ? Qh : (which == 1 ? Kh : Vh);
        _Float16* p = T + (size_t)(h * 128 + b) * 8192 + d0 + fr;
        const float bb = bias[colb + fr];
#pragma unroll
        for (int mi = 0; mi < 4; ++mi)
#pragma unroll
            for (int r = 0; r < 4; ++r) {
                const int n = nb + wrow + mi * 16 + fg * 4 + r;
                p[(size_t)n * 32] = (_Float16)(acc[mi][ni][r] + bb);
            }
    }
}

// ---------------------------------------------------------------------------
// Proj GEMM, 128x128 tile: A = attn output in head-major Q tensor
// (per-lane remapped global_load_lds source: k -> (h,d)), B fp32 reg-staged
// + cvt into swizzled LDS, C fp32 + bias.
// ---------------------------------------------------------------------------
__global__ __launch_bounds__(256) void k_proj(
    const _Float16* __restrict__ Qh,
    const float* __restrict__ B, int ldb,
    const float* __restrict__ bias,
    float* __restrict__ C, int ldc,
    int K, int nTilesN, int cpx)
{
    __shared__ _Float16 lA[128 * 64];
    __shared__ _Float16 lB[128 * 64];
    const int t    = threadIdx.x;
    const int lane = t & 63, wv = t >> 6;
    const int fr = lane & 15, fg = lane >> 4;
    const int wrow = (wv >> 1) * 64, wcol = (wv & 1) * 64;

    const int gid  = (blockIdx.x & 7) * cpx + (blockIdx.x >> 3);
    const int row0 = (gid / nTilesN) * 128;
    const int col0 = (gid % nTilesN) * 128;

    const int rowLane = lane >> 3;
    const int colOff  = ((lane & 7) ^ rowLane) * 8;
    const int wvr = wv * 32;

    const int bidx = row0 >> 8;
    const int nb   = (row0 & 255) + wvr + rowLane;
    _Float16* lAw = &lA[wvr * 64];

    // B staging: thread t owns row sb = t>>1, cols cb..cb+31 (fp32 -> fp16)
    const int sb = t >> 1, cb = (t & 1) * 32;
    const float* Bg = B + (size_t)(col0 + sb) * ldb + cb;

    f32x4 acc[4][4] = {};

    for (int k0 = 0; k0 < K; k0 += 64) {
        const int kc = k0 + colOff;          // global k of this lane's chunk
        const int hh = kc >> 5, dd = kc & 31;
        const _Float16* src = Qh + (size_t)(hh * 128 + bidx) * 8192 + dd;
#pragma unroll
        for (int i = 0; i < 4; ++i)
            async16(lAw + i * 8 * 64, src + (size_t)(nb + i * 8) * 32);
#pragma unroll
        for (int c = 0; c < 4; ++c) {
            float4 u = *(const float4*)(Bg + k0 + c * 8);
            float4 v = *(const float4*)(Bg + k0 + c * 8 + 4);
            f16x8 hv = { (_Float16)u.x, (_Float16)u.y, (_Float16)u.z, (_Float16)u.w,
                         (_Float16)v.x, (_Float16)v.y, (_Float16)v.z, (_Float16)v.w };
            const int ch = (cb >> 3) + c;
            *(f16x8*)&lB[sb * 64 + ((ch ^ (sb & 7)) * 8)] = hv;
        }
        __syncthreads();
#pragma unroll
        for (int kk = 0; kk < 2; ++kk) {
            f16x8 af[4], bf[4];
#pragma unroll
            for (int mi = 0; mi < 4; ++mi) {
                const int ra = wrow + mi * 16 + fr;
                const int rb = wcol + mi * 16 + fr;
                const int ch = ((kk * 4 + fg) ^ (fr & 7)) * 8;
                af[mi] = *(const f16x8*)&lA[ra * 64 + ch];
                bf[mi] = *(const f16x8*)&lB[rb * 64 + ch];
            }
#pragma unroll
            for (int mi = 0; mi < 4; ++mi)
#pragma unroll
                for (int ni = 0; ni < 4; ++ni)
                    acc[mi][ni] = MFMA16(af[mi], bf[ni], acc[mi][ni]);
        }
        __syncthreads();
    }
#pragma unroll
    for (int ni = 0; ni < 4; ++ni) {
        const int col = col0 + wcol + ni * 16 + fr;
        const float bb = bias[col];
#pragma unroll
        for (int mi = 0; mi < 4; ++mi)
#pragma unroll
            for (int r = 0; r < 4; ++r) {
                const int row = row0 + wrow + mi * 16 + fg * 4 + r;
                C[(size_t)row * ldc + col] = acc[mi][ni][r] + bb;
            }
    }
}

// ---------------------------------------------------------------------------
// Attention v3 (head-major): one block (4 waves) per (b,h).
// Q/K/V head-blocks are 16 KB CONTIGUOUS -> all reads coalesced.
// Output in place over the Q head-block (read-before-write per row-block).
// ---------------------------------------------------------------------------
#define ATT_SCALE 0.17677669529663687f  // 1/sqrt(32)

__global__ __launch_bounds__(256) void k_attn(
    _Float16* __restrict__ Qh, const _Float16* __restrict__ Kh,
    const _Float16* __restrict__ Vh, const _Float16* __restrict__ bm)
{
    __shared__ _Float16 lS[4][16 * 264];
    __shared__ _Float16 lVt[32 * 264];

    const int bh = blockIdx.x;
    const int b = bh >> 4, h = bh & 15;
    const int t = threadIdx.x, wv = t >> 6, lane = t & 63;
    const int fr = lane & 15, fg = lane >> 4;

    const size_t base = (size_t)(h * 128 + b) * 8192;
    _Float16* qb = Qh + base;
    const _Float16* kb = Kh + base;
    const _Float16* vb = Vh + base;
    const _Float16* bias_h = bm + (size_t)h * 256 * 256;

    // V^T into LDS: thread t owns V row t (64 B contiguous, coalesced)
    {
        const _Float16* vrow = vb + (size_t)t * 32;
        f16x8 v0 = *(const f16x8*)(vrow);
        f16x8 v1 = *(const f16x8*)(vrow + 8);
        f16x8 v2 = *(const f16x8*)(vrow + 16);
        f16x8 v3 = *(const f16x8*)(vrow + 24);
#pragma unroll
        for (int d = 0; d < 8; ++d) {
            lVt[(d     ) * 264 + t] = v0[d];
            lVt[(d +  8) * 264 + t] = v1[d];
            lVt[(d + 16) * 264 + t] = v2[d];
            lVt[(d + 24) * 264 + t] = v3[d];
        }
    }
    __syncthreads();

    _Float16* myS = &lS[wv][0];

    for (int rb = 0; rb < 4; ++rb) {
        const int r0 = wv * 64 + rb * 16;

        f16x8 aq = *(const f16x8*)(qb + (size_t)(r0 + fr) * 32 + fg * 8);

        // ---- pass 1: pure QK^T -> lS (fp16, scaled) ----
#pragma unroll 4
        for (int jt = 0; jt < 16; ++jt) {
            f16x8 bk = *(const f16x8*)(kb + (size_t)(jt * 16 + fr) * 32 + fg * 8);
            f32x4 s = { 0.f, 0.f, 0.f, 0.f };
            s = MFMA16(aq, bk, s);
#pragma unroll
            for (int r = 0; r < 4; ++r)
                myS[(fg * 4 + r) * 264 + jt * 16 + fr] = (_Float16)(s[r] * ATT_SCALE);
        }

        // bias row chunks (global, L2-resident)
        f16x8 tb[8];
        {
            const _Float16* brow = bias_h + (size_t)(r0 + fr) * 256 + fg * 8;
#pragma unroll
            for (int kc = 0; kc < 8; ++kc)
                tb[kc] = *(const f16x8*)(brow + kc * 32);
        }
        asm volatile("s_waitcnt lgkmcnt(0)" ::: "memory");

        // ---- pass 2: S+bias, in-lane 64-val max, exp, sum ----
        float vmax = -1e30f;
#pragma unroll
        for (int kc = 0; kc < 8; ++kc) {
            f16x8 sv = *(const f16x8*)(&myS[fr * 264 + kc * 32 + fg * 8]);
            tb[kc] = tb[kc] + sv;
#pragma unroll
            for (int j = 0; j < 8; ++j)
                vmax = fmaxf(vmax, (float)tb[kc][j]);
        }
        vmax = fmaxf(vmax, __shfl_xor(vmax, 16));
        vmax = fmaxf(vmax, __shfl_xor(vmax, 32));

        float rsum = 0.f;
#pragma unroll
        for (int kc = 0; kc < 8; ++kc) {
#pragma unroll
            for (int j = 0; j < 8; ++j) {
                float p = __expf((float)tb[kc][j] - vmax);
                rsum += p;
                tb[kc][j] = (_Float16)p;      // tb becomes the P A-fragment
            }
        }
        rsum += __shfl_xor(rsum, 16);
        rsum += __shfl_xor(rsum, 32);

        // ---- PV ----
        f32x4 o[2] = {};
#pragma unroll
        for (int kc = 0; kc < 8; ++kc) {
            f16x8 bv0 = *(const f16x8*)(&lVt[(fr     ) * 264 + kc * 32 + fg * 8]);
            f16x8 bv1 = *(const f16x8*)(&lVt[(fr + 16) * 264 + kc * 32 + fg * 8]);
            o[0] = MFMA16(tb[kc], bv0, o[0]);
            o[1] = MFMA16(tb[kc], bv1, o[1]);
        }
        float os[4];
#pragma unroll
        for (int r = 0; r < 4; ++r) os[r] = __shfl(rsum, fg * 4 + r);

        // in-place store over Q head-block rows of this row-block
#pragma unroll
        for (int ni = 0; ni < 2; ++ni)
#pragma unroll
            for (int r = 0; r < 4; ++r) {
                const int i = r0 + fg * 4 + r;
                qb[(size_t)i * 32 + ni * 16 + fr] = (_Float16)(o[ni][r] / os[r]);
            }
    }
}

// ---------------------------------------------------------------------------
extern "C" void kernel_launch(void* const* d_in, const int* in_sizes, int n_in,
                              void* d_out, int out_size, void* d_ws, size_t ws_size,
                              hipStream_t stream)
{
    (void)in_sizes; (void)n_in;
    const float* x      = (const float*)d_in[0];
    const float* qkv_w  = (const float*)d_in[2];
    const float* qkv_b  = (const float*)d_in[3];
    const float* proj_w = (const float*)d_in[4];
    const float* proj_b = (const float*)d_in[5];
    const float* rpb    = (const float*)d_in[6];
    float* out = (float*)d_out;

    const int M  = 128 * 256;  // 32768
    const int Cd = 512, N3 = 1536;
    const size_t HBN = (size_t)16 * 128 * 256 * 32;   // one head-major tensor

    // ws: Q/K/V head-major fp16 (3 x 33.5 MB). d_out doubles as scratch for
    // xh (32 MB) + qwh (1.5 MB) + bm (2 MB) — all dead before proj runs.
    const size_t need = 3 * HBN * sizeof(_Float16);
    if (ws_size < need) {
        (void)hipMemsetAsync(d_out, 0, (size_t)out_size * sizeof(float), stream);
        return;
    }

    _Float16* Qh = (_Float16*)d_ws;
    _Float16* Kh = Qh + HBN;
    _Float16* Vh = Kh + HBN;
    _Float16* xh   = (_Float16*)d_out;                    // 32 MB
    _Float16* qwh  = xh + (size_t)M * Cd;                 // +1.5 MB
    _Float16* bmat = qwh + (size_t)N3 * Cd;               // +2 MB

    k_cvt<<<dim3((M * Cd) / 2048), 256, 0, stream>>>(x, xh);
    k_cvt<<<dim3((N3 * Cd) / 2048), 256, 0, stream>>>(qkv_w, qwh);
    k_bias<<<dim3(16 * 256), 256, 0, stream>>>(rpb, bmat);

    k_gemm_qkv<<<dim3(3072), 256, 0, stream>>>(xh, Cd, qwh, Cd, qkv_b,
                                               Qh, Kh, Vh, Cd, 12, 384);
    k_attn<<<dim3(128 * 16), 256, 0, stream>>>(Qh, Kh, Vh, bmat);
    k_proj<<<dim3(1024), 256, 0, stream>>>(Qh, proj_w, Cd, proj_b,
                                           out, Cd, Cd, 4, 128);
}